// Round 10
// baseline (167.769 us; speedup 1.0000x reference)
//
#include <hip/hip_runtime.h>

#define B 4
#define TQ 256
#define TK 1024
#define QS 512
#define NN 128

// exp(2y) = exp2(y * 2*log2(e)); K1 stores E = exp2(TANH_SCALE * proj) so
// K2's tanh needs only one rcp: tanh(aq+ak) = 1 - 2/(1 + Eq*Ek).
#define TANH_SCALE 2.8853900817779268f
#define LOG2E 1.4426950408889634f
#define CTX_ELEMS ((size_t)B * TQ * QS)

__device__ __forceinline__ float fast_exp2(float x) {
#if __has_builtin(__builtin_amdgcn_exp2f)
    return __builtin_amdgcn_exp2f(x);
#else
    return exp2f(x);
#endif
}
__device__ __forceinline__ float fast_rcp(float x) {
#if __has_builtin(__builtin_amdgcn_rcpf)
    return __builtin_amdgcn_rcpf(x);
#else
    return 1.0f / x;
#endif
}

// ---------------------------------------------------------------------------
// K1: fused projections (R9 version). Row space = [1024 q ; 4096 k rows].
// Block: 8 rows x 128 cols, BK=32, 64 threads, 4x4 microtile, 640 blocks.
// Epilogue stores E = exp2(TANH_SCALE*proj): attq[q][n], attkT[b][n][k].
// ---------------------------------------------------------------------------
__global__ __launch_bounds__(64) void proj_kernel(
    const float* __restrict__ query, const float* __restrict__ keys,
    const float* __restrict__ Wq, const float* __restrict__ Wk,
    float* __restrict__ attq, float* __restrict__ attkT)
{
    __shared__ float As[32][12];   // [kk][row]; stride 12 keeps float4 align
    __shared__ float Bs[32][132];  // [kk][n], padded

    const int tid = threadIdx.x;
    const int rb = blockIdx.x * 8;
    const bool isq = (rb < B * TQ);
    const float* A = isq ? (query + (size_t)rb * QS)
                         : (keys + (size_t)(rb - B * TQ) * QS);
    const float* W = isq ? Wq : Wk;

    const int n0 = (tid & 31) * 4;
    const int q0 = (tid >> 5) * 4;
    float acc[4][4] = {};

    for (int k0 = 0; k0 < QS; k0 += 32) {
        {
            const int r = tid >> 3, c4 = tid & 7;
            const float4 v = *(const float4*)(A + (size_t)r * QS + k0 + c4 * 4);
            As[c4 * 4 + 0][r] = v.x;
            As[c4 * 4 + 1][r] = v.y;
            As[c4 * 4 + 2][r] = v.z;
            As[c4 * 4 + 3][r] = v.w;
        }
        {
            const int n4 = (tid & 31) * 4, kg = tid >> 5;
            #pragma unroll
            for (int j = 0; j < 16; ++j) {
                const int kk = kg + j * 2;
                *(float4*)&Bs[kk][n4] =
                    *(const float4*)(W + (size_t)(k0 + kk) * NN + n4);
            }
        }
        __syncthreads();
        #pragma unroll
        for (int kk = 0; kk < 32; ++kk) {
            const float4 a = *(const float4*)&As[kk][q0];
            const float4 b = *(const float4*)&Bs[kk][n0];
            const float av[4] = {a.x, a.y, a.z, a.w};
            #pragma unroll
            for (int i = 0; i < 4; ++i) {
                acc[i][0] = fmaf(av[i], b.x, acc[i][0]);
                acc[i][1] = fmaf(av[i], b.y, acc[i][1]);
                acc[i][2] = fmaf(av[i], b.z, acc[i][2]);
                acc[i][3] = fmaf(av[i], b.w, acc[i][3]);
            }
        }
        __syncthreads();
    }

    if (isq) {
        #pragma unroll
        for (int i = 0; i < 4; ++i) {
            float4 o;
            o.x = fast_exp2(acc[i][0] * TANH_SCALE);
            o.y = fast_exp2(acc[i][1] * TANH_SCALE);
            o.z = fast_exp2(acc[i][2] * TANH_SCALE);
            o.w = fast_exp2(acc[i][3] * TANH_SCALE);
            *(float4*)(attq + (size_t)(rb + q0 + i) * NN + n0) = o;
        }
    } else {
        #pragma unroll
        for (int i = 0; i < 4; ++i) {
            float4 o;
            o.x = fast_exp2(acc[i][0] * TANH_SCALE);
            o.y = fast_exp2(acc[i][1] * TANH_SCALE);
            o.z = fast_exp2(acc[i][2] * TANH_SCALE);
            o.w = fast_exp2(acc[i][3] * TANH_SCALE);
            *(float4*)&Bs[q0 + i][n0] = o;
        }
        __syncthreads();
        const int rk = rb - B * TQ;
        const int bb = rk >> 10;
        const int kbase = rk & 1023;
        #pragma unroll
        for (int h = 0; h < 2; ++h) {
            const int n = tid + h * 64;
            float* o = attkT + (size_t)bb * NN * TK + (size_t)n * TK + kbase;
            float4 t0, t1;
            t0.x = Bs[0][n]; t0.y = Bs[1][n]; t0.z = Bs[2][n]; t0.w = Bs[3][n];
            t1.x = Bs[4][n]; t1.y = Bs[5][n]; t1.z = Bs[6][n]; t1.w = Bs[7][n];
            *(float4*)(o + 0) = t0;
            *(float4*)(o + 4) = t1;
        }
    }
}

// ---------------------------------------------------------------------------
// K2: scores + softmax via the 1-rcp tanh. Block = (b, q-pair); 256 threads;
// lane owns 4 contiguous k (coalesced attkT). 512 blocks = 2 blocks/CU.
// Also zero-inits ctx (512*256*16B = exactly 2 MB) so K3 can atomicAdd —
// this removes the separate reduce kernel and split-K partial traffic.
// ---------------------------------------------------------------------------
__global__ __launch_bounds__(256) void score_softmax_kernel(
    const float* __restrict__ attq, const float* __restrict__ attkT,
    const float* __restrict__ vatt, float* __restrict__ wout,
    float4* __restrict__ ctxz)
{
    __shared__ float eqs[2][128];
    __shared__ float nv2[128];     // -2 * vatt
    __shared__ float red[2][8];

    const int tid = threadIdx.x;
    const int b = blockIdx.x >> 7;
    const int q0 = (blockIdx.x & 127) * 2;

    // zero the ctx region (becomes visible to K3 at kernel boundary)
    ctxz[(size_t)blockIdx.x * 256 + tid] = make_float4(0.f, 0.f, 0.f, 0.f);

    if (tid < 128) {
        eqs[0][tid] = attq[((size_t)b * TQ + q0) * NN + tid];
        nv2[tid] = -2.0f * vatt[tid];
    } else {
        eqs[1][tid & 127] = attq[((size_t)b * TQ + q0 + 1) * NN + (tid & 127)];
    }
    __syncthreads();

    const float* kt = attkT + (size_t)b * NN * TK + (size_t)tid * 4;
    float s[2][4] = {};

    #pragma unroll 8
    for (int n = 0; n < 128; ++n) {
        const float4 a = *(const float4*)(kt + (size_t)n * TK);
        const float e0 = eqs[0][n], e1 = eqs[1][n], nv = nv2[n];
        const float av[4] = {a.x, a.y, a.z, a.w};
        #pragma unroll
        for (int rr = 0; rr < 4; ++rr) {
            const float r0 = fast_rcp(fmaf(av[rr], e0, 1.0f));
            s[0][rr] = fmaf(nv, r0, s[0][rr]);
            const float r1 = fast_rcp(fmaf(av[rr], e1, 1.0f));
            s[1][rr] = fmaf(nv, r1, s[1][rr]);
        }
    }

    const int lane = tid & 63, wid = tid >> 6;
    #pragma unroll
    for (int qq = 0; qq < 2; ++qq) {
        float mm = fmaxf(fmaxf(s[qq][0], s[qq][1]), fmaxf(s[qq][2], s[qq][3]));
        #pragma unroll
        for (int off = 32; off > 0; off >>= 1)
            mm = fmaxf(mm, __shfl_xor(mm, off, 64));
        if (lane == 0) red[qq][wid] = mm;
    }
    __syncthreads();
    float m[2];
    m[0] = fmaxf(fmaxf(red[0][0], red[0][1]), fmaxf(red[0][2], red[0][3]));
    m[1] = fmaxf(fmaxf(red[1][0], red[1][1]), fmaxf(red[1][2], red[1][3]));

    float e[2][4];
    #pragma unroll
    for (int qq = 0; qq < 2; ++qq) {
        float ls = 0.f;
        #pragma unroll
        for (int i = 0; i < 4; ++i) {
            e[qq][i] = fast_exp2((s[qq][i] - m[qq]) * LOG2E);
            ls += e[qq][i];
        }
        #pragma unroll
        for (int off = 32; off > 0; off >>= 1)
            ls += __shfl_xor(ls, off, 64);
        if (lane == 0) red[qq][4 + wid] = ls;
    }
    __syncthreads();
    #pragma unroll
    for (int qq = 0; qq < 2; ++qq) {
        const float S = red[qq][4] + red[qq][5] + red[qq][6] + red[qq][7];
        const float inv = fast_rcp(S);
        float4 w4;
        w4.x = e[qq][0] * inv; w4.y = e[qq][1] * inv;
        w4.z = e[qq][2] * inv; w4.w = e[qq][3] * inv;
        *(float4*)(wout + ((size_t)b * TQ + q0 + qq) * TK + (size_t)tid * 4) = w4;
    }
}

// ---------------------------------------------------------------------------
// K3: context. Block tile 64q x 64d x 256k (split-K=4), 256 threads,
// 4x4 microtile, 512 blocks (2/CU). Epilogue: fp32 atomicAdd into the
// K2-zeroed ctx (4 writers/address) — no partials, no reduce kernel.
// ---------------------------------------------------------------------------
__global__ __launch_bounds__(256) void context_kernel(
    const float* __restrict__ keys, const float* __restrict__ w,
    float* __restrict__ ctx)
{
    __shared__ float Wst[32][66];  // [kk][q] transposed, stride 66 (8B align)
    __shared__ float Ks[32][64];   // [kk][d]

    const int tid = threadIdx.x;
    const int bid = blockIdx.x;
    const int b = bid >> 7;
    const int rem = bid & 127;
    const int qt = rem >> 5;        // 4 q-tiles of 64
    const int dt = (rem >> 2) & 7;  // 8 d-tiles of 64
    const int ks = rem & 3;         // k quarter

    const float* wb = w + (size_t)b * TQ * TK + (size_t)qt * 64 * TK + ks * 256;
    const float* kb = keys + (size_t)b * TK * QS + (size_t)ks * 256 * QS + dt * 64;

    const int d0 = (tid & 15) * 4;
    const int q0 = (tid >> 4) * 4;
    float acc[4][4] = {};

    const int wr = tid >> 2;        // 0..63: weights row
    const int wc = (tid & 3) * 8;   // 8 k's per thread

    for (int k0 = 0; k0 < 256; k0 += 32) {
        {
            const float4 v0 = *(const float4*)(wb + (size_t)wr * TK + k0 + wc);
            const float4 v1 = *(const float4*)(wb + (size_t)wr * TK + k0 + wc + 4);
            Wst[wc + 0][wr] = v0.x; Wst[wc + 1][wr] = v0.y;
            Wst[wc + 2][wr] = v0.z; Wst[wc + 3][wr] = v0.w;
            Wst[wc + 4][wr] = v1.x; Wst[wc + 5][wr] = v1.y;
            Wst[wc + 6][wr] = v1.z; Wst[wc + 7][wr] = v1.w;
        }
        {
            const int c = tid & 15, rr = tid >> 4;
            *(float4*)&Ks[rr][c * 4] =
                *(const float4*)(kb + (size_t)(k0 + rr) * QS + c * 4);
            *(float4*)&Ks[rr + 16][c * 4] =
                *(const float4*)(kb + (size_t)(k0 + rr + 16) * QS + c * 4);
        }
        __syncthreads();
        #pragma unroll
        for (int kk = 0; kk < 32; ++kk) {
            const float2 a01 = *(const float2*)&Wst[kk][q0];
            const float2 a23 = *(const float2*)&Wst[kk][q0 + 2];
            const float4 bb = *(const float4*)&Ks[kk][d0];
            const float av[4] = {a01.x, a01.y, a23.x, a23.y};
            #pragma unroll
            for (int i = 0; i < 4; ++i) {
                acc[i][0] = fmaf(av[i], bb.x, acc[i][0]);
                acc[i][1] = fmaf(av[i], bb.y, acc[i][1]);
                acc[i][2] = fmaf(av[i], bb.z, acc[i][2]);
                acc[i][3] = fmaf(av[i], bb.w, acc[i][3]);
            }
        }
        __syncthreads();
    }

    float* op = ctx + ((size_t)b * TQ + qt * 64 + q0) * QS + dt * 64 + d0;
    #pragma unroll
    for (int i = 0; i < 4; ++i)
        #pragma unroll
        for (int j = 0; j < 4; ++j)
            atomicAdd(op + (size_t)i * QS + j, acc[i][j]);
}

// ---------------------------------------------------------------------------
extern "C" void kernel_launch(void* const* d_in, const int* in_sizes, int n_in,
                              void* d_out, int out_size, void* d_ws, size_t ws_size,
                              hipStream_t stream) {
    const float* query = (const float*)d_in[0];  // (4,256,512)
    const float* keys  = (const float*)d_in[1];  // (4,1024,512)
    const float* Wq    = (const float*)d_in[2];  // (512,128)
    const float* Wk    = (const float*)d_in[3];  // (512,128)
    const float* vatt  = (const float*)d_in[4];  // (128,)

    float* ctx = (float*)d_out;                  // 4*256*512
    float* wts = ctx + CTX_ELEMS;                // 4*256*1024

    float* attq  = (float*)d_ws;                 // 4*256*128   (E-values)
    float* attkT = attq + (size_t)B * TQ * NN;   // 4*128*1024  (E, transposed)

    hipLaunchKernelGGL(proj_kernel, dim3((B * TQ + B * TK) / 8), dim3(64), 0,
                       stream, query, keys, Wq, Wk, attq, attkT);
    hipLaunchKernelGGL(score_softmax_kernel, dim3(B * TQ / 2), dim3(256), 0,
                       stream, attq, attkT, vatt, wts, (float4*)ctx);
    hipLaunchKernelGGL(context_kernel, dim3(512), dim3(256), 0,
                       stream, keys, wts, ctx);
}

// Round 11
// 134.936 us; speedup vs baseline: 1.2433x; 1.2433x over previous
//
#include <hip/hip_runtime.h>

#define B 4
#define TQ 256
#define TK 1024
#define QS 512
#define NN 128

// exp(2y) = exp2(y * 2*log2(e)); K1 stores E = exp2(TANH_SCALE * proj) so
// K2's tanh needs only one rcp: tanh(aq+ak) = 1 - 2/(1 + Eq*Ek).
#define TANH_SCALE 2.8853900817779268f
#define LOG2E 1.4426950408889634f
#define CTX_ELEMS ((size_t)B * TQ * QS)

__device__ __forceinline__ float fast_exp2(float x) {
#if __has_builtin(__builtin_amdgcn_exp2f)
    return __builtin_amdgcn_exp2f(x);
#else
    return exp2f(x);
#endif
}
__device__ __forceinline__ float fast_rcp(float x) {
#if __has_builtin(__builtin_amdgcn_rcpf)
    return __builtin_amdgcn_rcpf(x);
#else
    return 1.0f / x;
#endif
}

// ---------------------------------------------------------------------------
// K1: fused projections. Row space = [1024 q ; 4096 k rows].
// Block: 8 rows x 128 cols, BK=32, 64 threads, 4x4 microtile, 640 blocks.
// Epilogue stores E = exp2(TANH_SCALE*proj): attq[q][n], attkT[b][n][k].
// ---------------------------------------------------------------------------
__global__ __launch_bounds__(64) void proj_kernel(
    const float* __restrict__ query, const float* __restrict__ keys,
    const float* __restrict__ Wq, const float* __restrict__ Wk,
    float* __restrict__ attq, float* __restrict__ attkT)
{
    __shared__ float As[32][12];   // [kk][row]; stride 12 keeps float4 align
    __shared__ float Bs[32][132];  // [kk][n], padded

    const int tid = threadIdx.x;
    const int rb = blockIdx.x * 8;
    const bool isq = (rb < B * TQ);
    const float* A = isq ? (query + (size_t)rb * QS)
                         : (keys + (size_t)(rb - B * TQ) * QS);
    const float* W = isq ? Wq : Wk;

    const int n0 = (tid & 31) * 4;
    const int q0 = (tid >> 5) * 4;
    float acc[4][4] = {};

    for (int k0 = 0; k0 < QS; k0 += 32) {
        {
            const int r = tid >> 3, c4 = tid & 7;
            const float4 v = *(const float4*)(A + (size_t)r * QS + k0 + c4 * 4);
            As[c4 * 4 + 0][r] = v.x;
            As[c4 * 4 + 1][r] = v.y;
            As[c4 * 4 + 2][r] = v.z;
            As[c4 * 4 + 3][r] = v.w;
        }
        {
            const int n4 = (tid & 31) * 4, kg = tid >> 5;
            #pragma unroll
            for (int j = 0; j < 16; ++j) {
                const int kk = kg + j * 2;
                *(float4*)&Bs[kk][n4] =
                    *(const float4*)(W + (size_t)(k0 + kk) * NN + n4);
            }
        }
        __syncthreads();
        #pragma unroll
        for (int kk = 0; kk < 32; ++kk) {
            const float4 a = *(const float4*)&As[kk][q0];
            const float4 b = *(const float4*)&Bs[kk][n0];
            const float av[4] = {a.x, a.y, a.z, a.w};
            #pragma unroll
            for (int i = 0; i < 4; ++i) {
                acc[i][0] = fmaf(av[i], b.x, acc[i][0]);
                acc[i][1] = fmaf(av[i], b.y, acc[i][1]);
                acc[i][2] = fmaf(av[i], b.z, acc[i][2]);
                acc[i][3] = fmaf(av[i], b.w, acc[i][3]);
            }
        }
        __syncthreads();
    }

    if (isq) {
        #pragma unroll
        for (int i = 0; i < 4; ++i) {
            float4 o;
            o.x = fast_exp2(acc[i][0] * TANH_SCALE);
            o.y = fast_exp2(acc[i][1] * TANH_SCALE);
            o.z = fast_exp2(acc[i][2] * TANH_SCALE);
            o.w = fast_exp2(acc[i][3] * TANH_SCALE);
            *(float4*)(attq + (size_t)(rb + q0 + i) * NN + n0) = o;
        }
    } else {
        #pragma unroll
        for (int i = 0; i < 4; ++i) {
            float4 o;
            o.x = fast_exp2(acc[i][0] * TANH_SCALE);
            o.y = fast_exp2(acc[i][1] * TANH_SCALE);
            o.z = fast_exp2(acc[i][2] * TANH_SCALE);
            o.w = fast_exp2(acc[i][3] * TANH_SCALE);
            *(float4*)&Bs[q0 + i][n0] = o;
        }
        __syncthreads();
        const int rk = rb - B * TQ;
        const int bb = rk >> 10;
        const int kbase = rk & 1023;
        #pragma unroll
        for (int h = 0; h < 2; ++h) {
            const int n = tid + h * 64;
            float* o = attkT + (size_t)bb * NN * TK + (size_t)n * TK + kbase;
            float4 t0, t1;
            t0.x = Bs[0][n]; t0.y = Bs[1][n]; t0.z = Bs[2][n]; t0.w = Bs[3][n];
            t1.x = Bs[4][n]; t1.y = Bs[5][n]; t1.z = Bs[6][n]; t1.w = Bs[7][n];
            *(float4*)(o + 0) = t0;
            *(float4*)(o + 4) = t1;
        }
    }
}

// ---------------------------------------------------------------------------
// K2: scores + softmax via the 1-rcp tanh. Block = (b, q-pair); 256 threads;
// lane owns 4 contiguous k (coalesced attkT). 512 blocks = 2 blocks/CU.
// ---------------------------------------------------------------------------
__global__ __launch_bounds__(256) void score_softmax_kernel(
    const float* __restrict__ attq, const float* __restrict__ attkT,
    const float* __restrict__ vatt, float* __restrict__ wout)
{
    __shared__ float eqs[2][128];
    __shared__ float nv2[128];     // -2 * vatt
    __shared__ float red[2][8];

    const int tid = threadIdx.x;
    const int b = blockIdx.x >> 7;
    const int q0 = (blockIdx.x & 127) * 2;

    if (tid < 128) {
        eqs[0][tid] = attq[((size_t)b * TQ + q0) * NN + tid];
        nv2[tid] = -2.0f * vatt[tid];
    } else {
        eqs[1][tid & 127] = attq[((size_t)b * TQ + q0 + 1) * NN + (tid & 127)];
    }
    __syncthreads();

    const float* kt = attkT + (size_t)b * NN * TK + (size_t)tid * 4;
    float s[2][4] = {};

    #pragma unroll 8
    for (int n = 0; n < 128; ++n) {
        const float4 a = *(const float4*)(kt + (size_t)n * TK);
        const float e0 = eqs[0][n], e1 = eqs[1][n], nv = nv2[n];
        const float av[4] = {a.x, a.y, a.z, a.w};
        #pragma unroll
        for (int rr = 0; rr < 4; ++rr) {
            const float r0 = fast_rcp(fmaf(av[rr], e0, 1.0f));
            s[0][rr] = fmaf(nv, r0, s[0][rr]);
            const float r1 = fast_rcp(fmaf(av[rr], e1, 1.0f));
            s[1][rr] = fmaf(nv, r1, s[1][rr]);
        }
    }

    const int lane = tid & 63, wid = tid >> 6;
    #pragma unroll
    for (int qq = 0; qq < 2; ++qq) {
        float mm = fmaxf(fmaxf(s[qq][0], s[qq][1]), fmaxf(s[qq][2], s[qq][3]));
        #pragma unroll
        for (int off = 32; off > 0; off >>= 1)
            mm = fmaxf(mm, __shfl_xor(mm, off, 64));
        if (lane == 0) red[qq][wid] = mm;
    }
    __syncthreads();
    float m[2];
    m[0] = fmaxf(fmaxf(red[0][0], red[0][1]), fmaxf(red[0][2], red[0][3]));
    m[1] = fmaxf(fmaxf(red[1][0], red[1][1]), fmaxf(red[1][2], red[1][3]));

    float e[2][4];
    #pragma unroll
    for (int qq = 0; qq < 2; ++qq) {
        float ls = 0.f;
        #pragma unroll
        for (int i = 0; i < 4; ++i) {
            e[qq][i] = fast_exp2((s[qq][i] - m[qq]) * LOG2E);
            ls += e[qq][i];
        }
        #pragma unroll
        for (int off = 32; off > 0; off >>= 1)
            ls += __shfl_xor(ls, off, 64);
        if (lane == 0) red[qq][4 + wid] = ls;
    }
    __syncthreads();
    #pragma unroll
    for (int qq = 0; qq < 2; ++qq) {
        const float S = red[qq][4] + red[qq][5] + red[qq][6] + red[qq][7];
        const float inv = fast_rcp(S);
        float4 w4;
        w4.x = e[qq][0] * inv; w4.y = e[qq][1] * inv;
        w4.z = e[qq][2] * inv; w4.w = e[qq][3] * inv;
        *(float4*)(wout + ((size_t)b * TQ + q0 + qq) * TK + (size_t)tid * 4) = w4;
    }
}

// ---------------------------------------------------------------------------
// K3: context partials. Block tile 64q x 64d x 256k (split-K=4), 256 threads,
// 4x4 microtile. Grid 512 blocks (2/CU). Plain partial stores — atomics
// tested in R10 cost +25 us (2.1M fp32 atomicAdds serialize in L2).
// ---------------------------------------------------------------------------
__global__ __launch_bounds__(256) void context_kernel(
    const float* __restrict__ keys, const float* __restrict__ w,
    float* __restrict__ ctxp)
{
    __shared__ float Wst[32][66];  // [kk][q] transposed, stride 66 (8B align)
    __shared__ float Ks[32][64];   // [kk][d]

    const int tid = threadIdx.x;
    const int bid = blockIdx.x;
    const int b = bid >> 7;
    const int rem = bid & 127;
    const int qt = rem >> 5;        // 4 q-tiles of 64
    const int dt = (rem >> 2) & 7;  // 8 d-tiles of 64
    const int ks = rem & 3;         // k quarter

    const float* wb = w + (size_t)b * TQ * TK + (size_t)qt * 64 * TK + ks * 256;
    const float* kb = keys + (size_t)b * TK * QS + (size_t)ks * 256 * QS + dt * 64;

    const int d0 = (tid & 15) * 4;
    const int q0 = (tid >> 4) * 4;
    float acc[4][4] = {};

    const int wr = tid >> 2;        // 0..63: weights row
    const int wc = (tid & 3) * 8;   // 8 k's per thread

    for (int k0 = 0; k0 < 256; k0 += 32) {
        {
            const float4 v0 = *(const float4*)(wb + (size_t)wr * TK + k0 + wc);
            const float4 v1 = *(const float4*)(wb + (size_t)wr * TK + k0 + wc + 4);
            Wst[wc + 0][wr] = v0.x; Wst[wc + 1][wr] = v0.y;
            Wst[wc + 2][wr] = v0.z; Wst[wc + 3][wr] = v0.w;
            Wst[wc + 4][wr] = v1.x; Wst[wc + 5][wr] = v1.y;
            Wst[wc + 6][wr] = v1.z; Wst[wc + 7][wr] = v1.w;
        }
        {
            const int c = tid & 15, rr = tid >> 4;
            *(float4*)&Ks[rr][c * 4] =
                *(const float4*)(kb + (size_t)(k0 + rr) * QS + c * 4);
            *(float4*)&Ks[rr + 16][c * 4] =
                *(const float4*)(kb + (size_t)(k0 + rr + 16) * QS + c * 4);
        }
        __syncthreads();
        #pragma unroll
        for (int kk = 0; kk < 32; ++kk) {
            const float2 a01 = *(const float2*)&Wst[kk][q0];
            const float2 a23 = *(const float2*)&Wst[kk][q0 + 2];
            const float4 bb = *(const float4*)&Ks[kk][d0];
            const float av[4] = {a01.x, a01.y, a23.x, a23.y};
            #pragma unroll
            for (int i = 0; i < 4; ++i) {
                acc[i][0] = fmaf(av[i], bb.x, acc[i][0]);
                acc[i][1] = fmaf(av[i], bb.y, acc[i][1]);
                acc[i][2] = fmaf(av[i], bb.z, acc[i][2]);
                acc[i][3] = fmaf(av[i], bb.w, acc[i][3]);
            }
        }
        __syncthreads();
    }

    float* op = ctxp + (size_t)ks * CTX_ELEMS
              + ((size_t)b * TQ + qt * 64 + q0) * QS + dt * 64 + d0;
    #pragma unroll
    for (int i = 0; i < 4; ++i) {
        float4 o;
        o.x = acc[i][0]; o.y = acc[i][1]; o.z = acc[i][2]; o.w = acc[i][3];
        *(float4*)(op + (size_t)i * QS) = o;
    }
}

// ---------------------------------------------------------------------------
// K4: reduce the 4 split-K partials into ctx. 131072 float4 outputs.
// ---------------------------------------------------------------------------
__global__ __launch_bounds__(256) void reduce_kernel(
    const float4* __restrict__ ctxp, float4* __restrict__ ctx)
{
    const size_t idx = (size_t)blockIdx.x * 256 + threadIdx.x;
    const size_t stride = CTX_ELEMS / 4;
    const float4 a = ctxp[idx];
    const float4 b = ctxp[idx + stride];
    const float4 c = ctxp[idx + 2 * stride];
    const float4 d = ctxp[idx + 3 * stride];
    float4 o;
    o.x = (a.x + b.x) + (c.x + d.x);
    o.y = (a.y + b.y) + (c.y + d.y);
    o.z = (a.z + b.z) + (c.z + d.z);
    o.w = (a.w + b.w) + (c.w + d.w);
    ctx[idx] = o;
}

// ---------------------------------------------------------------------------
extern "C" void kernel_launch(void* const* d_in, const int* in_sizes, int n_in,
                              void* d_out, int out_size, void* d_ws, size_t ws_size,
                              hipStream_t stream) {
    const float* query = (const float*)d_in[0];  // (4,256,512)
    const float* keys  = (const float*)d_in[1];  // (4,1024,512)
    const float* Wq    = (const float*)d_in[2];  // (512,128)
    const float* Wk    = (const float*)d_in[3];  // (512,128)
    const float* vatt  = (const float*)d_in[4];  // (128,)

    float* ctx = (float*)d_out;                  // 4*256*512
    float* wts = ctx + CTX_ELEMS;                // 4*256*1024

    float* attq  = (float*)d_ws;                 // 4*256*128   (E-values)
    float* attkT = attq + (size_t)B * TQ * NN;   // 4*128*1024  (E, transposed)
    float* ctxp  = attkT + (size_t)B * NN * TK;  // 4 * CTX_ELEMS partials

    hipLaunchKernelGGL(proj_kernel, dim3((B * TQ + B * TK) / 8), dim3(64), 0,
                       stream, query, keys, Wq, Wk, attq, attkT);
    hipLaunchKernelGGL(score_softmax_kernel, dim3(B * TQ / 2), dim3(256), 0,
                       stream, attq, attkT, vatt, wts);
    hipLaunchKernelGGL(context_kernel, dim3(512), dim3(256), 0,
                       stream, keys, wts, ctxp);
    hipLaunchKernelGGL(reduce_kernel, dim3((unsigned)(CTX_ELEMS / 4 / 256)), dim3(256), 0,
                       stream, (const float4*)ctxp, (float4*)ctx);
}